// Round 8
// baseline (5853.763 us; speedup 1.0000x reference)
//
#include <hip/hip_runtime.h>

#define BB 512
#define TT 512
#define FF 64
#define HH 128
#define NCLS 10
#define WT 4            // LDS staging window (steps)
#define CH 16           // producer->consumer chunk (steps)
#define HBP 136         // padded h row (shorts): 272 B, 16B-divisible
#define HBSZ (16 * HBP)

typedef __attribute__((ext_vector_type(8))) short short8;
typedef __attribute__((ext_vector_type(4))) float f32x4;

#define NLOG2E  (-1.4426950408889634f)
#define N2LOG2E (-2.8853900817779268f)

__device__ __forceinline__ unsigned short f2bf(float f) {
    union { float f; unsigned u; } v; v.f = f;
    unsigned r = v.u + 0x7FFFu + ((v.u >> 16) & 1u);   // RNE
    return (unsigned short)(r >> 16);
}

// LDS-only barrier: drain lgkmcnt + raw s_barrier (no vmcnt drain).
__device__ __forceinline__ void bar_lds() {
    asm volatile("s_waitcnt lgkmcnt(0)" ::: "memory");
    __builtin_amdgcn_s_barrier();
    asm volatile("" ::: "memory");
}

// ---- flag protocol (per-half: t is the half-local tid, f the half's flag) --
__device__ __forceinline__ void wait_flag(int* f, int t) {
    if (t == 0) {
        while (__hip_atomic_load(f, __ATOMIC_ACQUIRE, __HIP_MEMORY_SCOPE_AGENT) == 0)
            __builtin_amdgcn_s_sleep(2);
    }
    __syncthreads();   // joins BOTH halves (uniform call sites)
    (void)__hip_atomic_load(f, __ATOMIC_ACQUIRE, __HIP_MEMORY_SCOPE_AGENT);
}
__device__ __forceinline__ void set_flag(int* f, int t) {
    __threadfence();
    __syncthreads();   // doubles as the boundary barrier on chunk-end steps
    if (t == 0)
        __hip_atomic_fetch_add(f, 1, __ATOMIC_RELEASE, __HIP_MEMORY_SCOPE_AGENT);
}

// ---------------------------------------------------------------------------
// R8: two independent 16-row scans per 1024-thread block ("R3 across waves").
// Waves 0-7 run group A, waves 8-15 run group B -- each wave executes the
// VERBATIM R6 per-step code (same issue count), sharing only the block
// barrier. Each SIMD hosts 2A+2B waves: B's issue fills A's post-barrier
// latency stall (the ~2000cyc FIXED component) and vice versa. Both halves
// hit every barrier the same number of times (conditions depend only on tw).
// ---------------------------------------------------------------------------
template<int XW, bool IS_L1>
__device__ void layer_scan(
    const void* __restrict__ xin_,
    const float* __restrict__ w_ih, const float* __restrict__ w_hh,
    const float* __restrict__ b_ih, const float* __restrict__ b_hh,
    unsigned short* __restrict__ out1,   // L1: h stream out (bf16)
    float* __restrict__ h2s,             // L2: final h out (fp32)
    int* __restrict__ f_in,              // L2: per-chunk input flags
    int* __restrict__ f_out,             // L1: per-chunk done flags
    int grp,                             // 16-row group index (0..31)
    unsigned short* xw, unsigned short* hb, int t)
{
    const int w = t >> 6, l = t & 63, lm = l & 15, kb = l >> 4;
    const int u = w * 16 + lm;           // owned hidden unit
    constexpr int KT  = (XW + HH) / 32;  // 6 (L1) / 8 (L2)
    constexpr int XKT = XW / 32;         // 2 / 4
    constexpr int HKT = HH / 32;         // 4
    constexpr int XWP = XW + 8;          // padded LDS row (shorts)
    constexpr int XBUF = WT * 16 * XWP;  // one window buffer (shorts)

    // --- stationary B fragments + bias: gate g = j*128 + u; x-kts then h-kts ---
    short8 bf[4][KT];
    float bv[4];
    #pragma unroll
    for (int j = 0; j < 4; j++) {
        const int g = j * 128 + u;
        bv[j] = b_ih[g] + b_hh[g];
        #pragma unroll
        for (int kt = 0; kt < KT; kt++) {
            const int k0 = kt * 32 + kb * 8;
            const float* s = (k0 < XW) ? (w_ih + (size_t)g * XW + k0)
                                       : (w_hh + (size_t)g * HH + (k0 - XW));
            short8 tq;
            #pragma unroll
            for (int q = 0; q < 8; q++) tq[q] = (short)f2bf(s[q]);
            bf[j][kt] = tq;
        }
    }

    for (int i = t; i < 2 * HBSZ; i += 512) hb[i] = 0;

    float c[4] = {0.f, 0.f, 0.f, 0.f}, hlast[4] = {0.f, 0.f, 0.f, 0.f};

    float4 pfa, pfb;     // L1: 8 fp32
    uint4  pf0, pf1;     // L2: 16 bf16

    // ---- helper lambdas (all inlined; verbatim R6 with tid->t, bg*16->grp*16) ----
    auto PREFETCH = [&](int t0) {
        if (IS_L1) {
            const float* x = (const float*)xin_;
            const int flat = t * 8;
            const int tt2 = flat >> 10, row = (flat >> 6) & 15, k = flat & 63;
            const float* s = x + (((size_t)(grp * 16 + row)) * TT + t0 + tt2) * FF + k;
            pfa = *(const float4*)s; pfb = *(const float4*)(s + 4);
        } else {
            const unsigned short* o1 = (const unsigned short*)xin_;
            const int flat = t * 16;
            const int tt2 = flat >> 11, row = (flat >> 7) & 15, k = flat & 127;
            const unsigned short* s = o1 + (((size_t)(grp * 16 + row)) * TT + t0 + tt2) * HH + k;
            pf0 = *(const uint4*)s; pf1 = *(const uint4*)(s + 8);
        }
    };
    auto COMMIT = [&](int bufidx) {
        unsigned short* buf = xw + bufidx * XBUF;
        if (IS_L1) {
            const int flat = t * 8;
            const int tt2 = flat >> 10, row = (flat >> 6) & 15, k = flat & 63;
            uint4 pv;
            pv.x = (unsigned)f2bf(pfa.x) | ((unsigned)f2bf(pfa.y) << 16);
            pv.y = (unsigned)f2bf(pfa.z) | ((unsigned)f2bf(pfa.w) << 16);
            pv.z = (unsigned)f2bf(pfb.x) | ((unsigned)f2bf(pfb.y) << 16);
            pv.w = (unsigned)f2bf(pfb.z) | ((unsigned)f2bf(pfb.w) << 16);
            *(uint4*)&buf[(tt2 * 16 + row) * XWP + k] = pv;
        } else {
            const int flat = t * 16;
            const int tt2 = flat >> 11, row = (flat >> 7) & 15, k = flat & 127;
            *(uint4*)&buf[(tt2 * 16 + row) * XWP + k]     = pf0;
            *(uint4*)&buf[(tt2 * 16 + row) * XWP + k + 8] = pf1;
        }
    };
    auto XB = [&](f32x4 (&dst)[4], const unsigned short* wbase, int ts) {
        #pragma unroll
        for (int j = 0; j < 4; j++) dst[j] = (f32x4){bv[j], bv[j], bv[j], bv[j]};
        const unsigned short* ab = wbase + (ts * 16 + lm) * XWP + kb * 8;
        #pragma unroll
        for (int kt = 0; kt < XKT; kt++) {
            const short8 a = *(const short8*)(ab + kt * 32);
            dst[0] = __builtin_amdgcn_mfma_f32_16x16x32_bf16(a, bf[0][kt], dst[0], 0, 0, 0);
            dst[1] = __builtin_amdgcn_mfma_f32_16x16x32_bf16(a, bf[1][kt], dst[1], 0, 0, 0);
            dst[2] = __builtin_amdgcn_mfma_f32_16x16x32_bf16(a, bf[2][kt], dst[2], 0, 0, 0);
            dst[3] = __builtin_amdgcn_mfma_f32_16x16x32_bf16(a, bf[3][kt], dst[3], 0, 0, 0);
        }
    };
    auto HM = [&](f32x4 (&a)[4], int par) {
        const unsigned short* hbase = hb + par * HBSZ + lm * HBP + kb * 8;
        #pragma unroll
        for (int kt = 0; kt < HKT; kt++) {
            const short8 av = *(const short8*)(hbase + kt * 32);
            a[0] = __builtin_amdgcn_mfma_f32_16x16x32_bf16(av, bf[0][XKT + kt], a[0], 0, 0, 0);
            a[1] = __builtin_amdgcn_mfma_f32_16x16x32_bf16(av, bf[1][XKT + kt], a[1], 0, 0, 0);
            a[2] = __builtin_amdgcn_mfma_f32_16x16x32_bf16(av, bf[2][XKT + kt], a[2], 0, 0, 0);
            a[3] = __builtin_amdgcn_mfma_f32_16x16x32_bf16(av, bf[3][XKT + kt], a[3], 0, 0, 0);
        }
    };
    auto EPI = [&](f32x4 (&a)[4], int tl) {
        float hv[4];
        #pragma unroll
        for (int r = 0; r < 4; r++) {
            const float ef = __builtin_amdgcn_exp2f(NLOG2E * a[1][r]);
            const float fv = __builtin_amdgcn_rcpf(1.f + ef);
            const float ea = __builtin_amdgcn_exp2f(NLOG2E * a[0][r]);
            const float g2 = fmaxf(a[2][r], -30.f);
            const float eg = __builtin_amdgcn_exp2f(N2LOG2E * g2);
            const float ig = (1.f - eg) * __builtin_amdgcn_rcpf((1.f + ea) * (1.f + eg));
            c[r] = fv * c[r] + ig;
            const float eo = __builtin_amdgcn_exp2f(NLOG2E * a[3][r]);
            const float cc = fmaxf(c[r], -30.f);
            const float ec = __builtin_amdgcn_exp2f(N2LOG2E * cc);
            hv[r] = (1.f - ec) * __builtin_amdgcn_rcpf((1.f + eo) * (1.f + ec));
            hlast[r] = hv[r];
        }
        unsigned p01, p23;   // packed bf16 pairs, RNE
        asm("v_cvt_pk_bf16_f32 %0, %1, %2" : "=v"(p01) : "v"(hv[0]), "v"(hv[1]));
        asm("v_cvt_pk_bf16_f32 %0, %1, %2" : "=v"(p23) : "v"(hv[2]), "v"(hv[3]));
        const unsigned short h0 = (unsigned short)(p01 & 0xffffu);
        const unsigned short h1 = (unsigned short)(p01 >> 16);
        const unsigned short h2 = (unsigned short)(p23 & 0xffffu);
        const unsigned short h3 = (unsigned short)(p23 >> 16);
        unsigned short* hw = hb + ((tl + 1) & 1) * HBSZ + (kb * 4) * HBP + u;
        hw[0] = h0; hw[HBP] = h1; hw[2 * HBP] = h2; hw[3 * HBP] = h3;
        if (IS_L1) {
            unsigned short* op = out1 + (((size_t)(grp * 16 + kb * 4)) * TT + tl) * HH + u;
            op[0] = h0;
            op[(size_t)TT * HH] = h1;
            op[(size_t)2 * TT * HH] = h2;
            op[(size_t)3 * TT * HH] = h3;
        }
    };

    // ---- preamble: window-0 prefetch+commit, then prefetch window 1 ----
    if (!IS_L1) wait_flag(&f_in[0], t);   // covers steps 0..15 (chunk 0)
    PREFETCH(0);
    COMMIT(0);
    PREFETCH(WT);                      // invariant: regs hold W(tw+WT) at step 3
    bar_lds();

    for (int tw = 0; tw < TT; tw += WT) {
        const unsigned short* wbase = xw + ((tw >> 2) & 1) * XBUF;
        const int wst = tw + WT;           // next window start (commit target)
        const int pnext = tw + 2 * WT;     // prefetch target (refills regs)
        f32x4 xc0[4], xc1[4], xn0[4], xn1[4];

        // ---- step 0 ----
        XB(xc0, wbase, 0);
        XB(xc1, wbase, 1);              // hides under epi0
        HM(xc0, 0);
        EPI(xc0, tw + 0);
        bar_lds();
        // ---- step 1 ----
        XB(xn0, wbase, 2);              // hides under epi1
        HM(xc1, 1);
        EPI(xc1, tw + 1);
        bar_lds();
        // ---- step 2 ----
        XB(xn1, wbase, 3);              // hides under epi2
        HM(xn0, 0);
        EPI(xn0, tw + 2);
        bar_lds();
        // ---- step 3: + window commit & prefetch (merged boundary) ----
        HM(xn1, 1);
        if (wst < TT) COMMIT((wst >> 2) & 1);   // regs = W(wst); other buffer dead
        EPI(xn1, tw + 3);
        if (pnext < TT) {
            if (!IS_L1 && (pnext & (CH - 1)) == 0) wait_flag(&f_in[pnext >> 4], t);
            PREFETCH(pnext);            // consumed at next window's step-3 commit
        }
        if (IS_L1 && ((tw + 3) & (CH - 1)) == (CH - 1)) {
            set_flag(&f_out[(tw + 3) >> 4], t); // fence + barrier + flag
        } else {
            bar_lds();                          // boundary barrier (covers commit)
        }
    }

    if (!IS_L1) {
        #pragma unroll
        for (int r = 0; r < 4; r++)
            h2s[((size_t)(grp * 16 + kb * 4 + r)) * HH + u] = hlast[r];
    }
}

// bid 0-15: layer-1 (2 groups per block). bid 16-31: layer-2.
// bid and bid+16 share bid%8 -> same XCD for out1 L2-cache locality.
__global__ __launch_bounds__(1024, 4) void lstm_pipe(
    const float* __restrict__ x,
    const float* __restrict__ w1_ih, const float* __restrict__ w1_hh,
    const float* __restrict__ b1_ih, const float* __restrict__ b1_hh,
    const float* __restrict__ w2_ih, const float* __restrict__ w2_hh,
    const float* __restrict__ b2_ih, const float* __restrict__ b2_hh,
    unsigned short* __restrict__ out1, float* __restrict__ h2s,
    int* __restrict__ flags)
{
    __shared__ __align__(16) unsigned short xw[2][2 * WT * 16 * (HH + 8)]; // 69632 B
    __shared__ __align__(16) unsigned short hb[2][2 * HBSZ];               // 17408 B
    const int bid = blockIdx.x;
    const int half = threadIdx.x >> 9;       // wave-uniform
    const int t = threadIdx.x & 511;
    if (bid < 16) {
        const int grp = bid * 2 + half;
        layer_scan<FF, true >(x, w1_ih, w1_hh, b1_ih, b1_hh, out1, nullptr,
                              nullptr, &flags[grp * 32], grp, xw[half], hb[half], t);
    } else {
        const int grp = (bid - 16) * 2 + half;
        layer_scan<HH, false>(out1, w2_ih, w2_hh, b2_ih, b2_hh, nullptr, h2s,
                              &flags[grp * 32], nullptr, grp, xw[half], hb[half], t);
    }
}

__global__ void final_kernel(const float* __restrict__ h2s,
                             const float* __restrict__ w_fc,
                             const float* __restrict__ b_fc,
                             float* __restrict__ out)
{
    const int idx = blockIdx.x * blockDim.x + threadIdx.x;
    if (idx >= BB * NCLS) return;
    const int b = idx / NCLS, cls = idx % NCLS;
    const float* hp = h2s + (size_t)b * HH;
    const float* wp = w_fc + (size_t)cls * HH;
    float acc = b_fc[cls];
    #pragma unroll 8
    for (int k = 0; k < HH; k++) acc += hp[k] * wp[k];
    const float e = __builtin_amdgcn_exp2f(NLOG2E * acc);
    out[idx] = __builtin_amdgcn_rcpf(1.0f + e);
}

extern "C" void kernel_launch(void* const* d_in, const int* in_sizes, int n_in,
                              void* d_out, int out_size, void* d_ws, size_t ws_size,
                              hipStream_t stream)
{
    const float* x     = (const float*)d_in[0];
    const float* w1_ih = (const float*)d_in[1];
    const float* w1_hh = (const float*)d_in[2];
    const float* b1_ih = (const float*)d_in[3];
    const float* b1_hh = (const float*)d_in[4];
    const float* w2_ih = (const float*)d_in[5];
    const float* w2_hh = (const float*)d_in[6];
    const float* b2_ih = (const float*)d_in[7];
    const float* b2_hh = (const float*)d_in[8];
    const float* w_fc  = (const float*)d_in[9];
    const float* b_fc  = (const float*)d_in[10];
    float* out = (float*)d_out;

    // workspace: [h2s fp32 256KB | flags 4KB | out1 bf16 67MB]
    char* ws = (char*)d_ws;
    float* h2s = (float*)ws;                 ws += (size_t)BB * HH * sizeof(float);
    int* flags = (int*)ws;                   ws += 32 * 32 * sizeof(int);
    unsigned short* out1 = (unsigned short*)ws;

    hipMemsetAsync(flags, 0, 32 * 32 * sizeof(int), stream);
    lstm_pipe<<<32, 1024, 0, stream>>>(x, w1_ih, w1_hh, b1_ih, b1_hh,
                                       w2_ih, w2_hh, b2_ih, b2_hh,
                                       out1, h2s, flags);
    final_kernel<<<(BB * NCLS + 255) / 256, 256, 0, stream>>>(h2s, w_fc, b_fc, out);
}

// Round 9
// 5834.512 us; speedup vs baseline: 1.0033x; 1.0033x over previous
//
#include <hip/hip_runtime.h>

#define BB 512
#define TT 512
#define FF 64
#define HH 128
#define NCLS 10
#define WT 4            // LDS staging window (steps)
#define CH 16           // producer->consumer chunk (steps)
#define HBP 136         // padded h row (shorts): 272 B, 16B-divisible
#define HBSZ (16 * HBP)

typedef __attribute__((ext_vector_type(8))) short short8;
typedef __attribute__((ext_vector_type(4))) float f32x4;

#define NLOG2E  (-1.4426950408889634f)
#define N2LOG2E (-2.8853900817779268f)

__device__ __forceinline__ unsigned short f2bf(float f) {
    union { float f; unsigned u; } v; v.f = f;
    unsigned r = v.u + 0x7FFFu + ((v.u >> 16) & 1u);   // RNE
    return (unsigned short)(r >> 16);
}

// LDS-only barrier: drain lgkmcnt + raw s_barrier (no vmcnt drain).
__device__ __forceinline__ void bar_lds() {
    asm volatile("s_waitcnt lgkmcnt(0)" ::: "memory");
    __builtin_amdgcn_s_barrier();
    asm volatile("" ::: "memory");
}

// ---- flag protocol (per-half: t is the half-local tid, f the half's flag) --
__device__ __forceinline__ void wait_flag(int* f, int t) {
    if (t == 0) {
        while (__hip_atomic_load(f, __ATOMIC_ACQUIRE, __HIP_MEMORY_SCOPE_AGENT) == 0)
            __builtin_amdgcn_s_sleep(2);
    }
    __syncthreads();   // joins BOTH halves (uniform call sites)
    (void)__hip_atomic_load(f, __ATOMIC_ACQUIRE, __HIP_MEMORY_SCOPE_AGENT);
}
__device__ __forceinline__ void set_flag(int* f, int t) {
    __threadfence();
    __syncthreads();   // doubles as the boundary barrier on chunk-end steps
    if (t == 0)
        __hip_atomic_fetch_add(f, 1, __ATOMIC_RELEASE, __HIP_MEMORY_SCOPE_AGENT);
}

// ---------------------------------------------------------------------------
// R9 = R8 (two independent 16-row scans per 1024-thread block; per-wave code
// verbatim R6) + amdgpu_waves_per_eu(4,4). R8's 7.4x regression was a spill:
// the allocator targeted 8 waves/EU -> 64 VGPRs -> 567MB scratch traffic.
// Pinning min=max=4 waves/EU (exactly one 16-wave block per CU) restores the
// 128-VGPR budget the R6 code needs, making this a clean test of the
// co-residency mechanism: 2A+2B waves per SIMD, B's issue fills A's
// post-barrier stall and vice versa.
// ---------------------------------------------------------------------------
template<int XW, bool IS_L1>
__device__ void layer_scan(
    const void* __restrict__ xin_,
    const float* __restrict__ w_ih, const float* __restrict__ w_hh,
    const float* __restrict__ b_ih, const float* __restrict__ b_hh,
    unsigned short* __restrict__ out1,   // L1: h stream out (bf16)
    float* __restrict__ h2s,             // L2: final h out (fp32)
    int* __restrict__ f_in,              // L2: per-chunk input flags
    int* __restrict__ f_out,             // L1: per-chunk done flags
    int grp,                             // 16-row group index (0..31)
    unsigned short* xw, unsigned short* hb, int t)
{
    const int w = t >> 6, l = t & 63, lm = l & 15, kb = l >> 4;
    const int u = w * 16 + lm;           // owned hidden unit
    constexpr int KT  = (XW + HH) / 32;  // 6 (L1) / 8 (L2)
    constexpr int XKT = XW / 32;         // 2 / 4
    constexpr int HKT = HH / 32;         // 4
    constexpr int XWP = XW + 8;          // padded LDS row (shorts)
    constexpr int XBUF = WT * 16 * XWP;  // one window buffer (shorts)

    // --- stationary B fragments + bias: gate g = j*128 + u; x-kts then h-kts ---
    short8 bf[4][KT];
    float bv[4];
    #pragma unroll
    for (int j = 0; j < 4; j++) {
        const int g = j * 128 + u;
        bv[j] = b_ih[g] + b_hh[g];
        #pragma unroll
        for (int kt = 0; kt < KT; kt++) {
            const int k0 = kt * 32 + kb * 8;
            const float* s = (k0 < XW) ? (w_ih + (size_t)g * XW + k0)
                                       : (w_hh + (size_t)g * HH + (k0 - XW));
            short8 tq;
            #pragma unroll
            for (int q = 0; q < 8; q++) tq[q] = (short)f2bf(s[q]);
            bf[j][kt] = tq;
        }
    }

    for (int i = t; i < 2 * HBSZ; i += 512) hb[i] = 0;

    float c[4] = {0.f, 0.f, 0.f, 0.f}, hlast[4] = {0.f, 0.f, 0.f, 0.f};

    float4 pfa, pfb;     // L1: 8 fp32
    uint4  pf0, pf1;     // L2: 16 bf16

    // ---- helper lambdas (all inlined; verbatim R6 with tid->t, bg*16->grp*16) ----
    auto PREFETCH = [&](int t0) {
        if (IS_L1) {
            const float* x = (const float*)xin_;
            const int flat = t * 8;
            const int tt2 = flat >> 10, row = (flat >> 6) & 15, k = flat & 63;
            const float* s = x + (((size_t)(grp * 16 + row)) * TT + t0 + tt2) * FF + k;
            pfa = *(const float4*)s; pfb = *(const float4*)(s + 4);
        } else {
            const unsigned short* o1 = (const unsigned short*)xin_;
            const int flat = t * 16;
            const int tt2 = flat >> 11, row = (flat >> 7) & 15, k = flat & 127;
            const unsigned short* s = o1 + (((size_t)(grp * 16 + row)) * TT + t0 + tt2) * HH + k;
            pf0 = *(const uint4*)s; pf1 = *(const uint4*)(s + 8);
        }
    };
    auto COMMIT = [&](int bufidx) {
        unsigned short* buf = xw + bufidx * XBUF;
        if (IS_L1) {
            const int flat = t * 8;
            const int tt2 = flat >> 10, row = (flat >> 6) & 15, k = flat & 63;
            uint4 pv;
            pv.x = (unsigned)f2bf(pfa.x) | ((unsigned)f2bf(pfa.y) << 16);
            pv.y = (unsigned)f2bf(pfa.z) | ((unsigned)f2bf(pfa.w) << 16);
            pv.z = (unsigned)f2bf(pfb.x) | ((unsigned)f2bf(pfb.y) << 16);
            pv.w = (unsigned)f2bf(pfb.z) | ((unsigned)f2bf(pfb.w) << 16);
            *(uint4*)&buf[(tt2 * 16 + row) * XWP + k] = pv;
        } else {
            const int flat = t * 16;
            const int tt2 = flat >> 11, row = (flat >> 7) & 15, k = flat & 127;
            *(uint4*)&buf[(tt2 * 16 + row) * XWP + k]     = pf0;
            *(uint4*)&buf[(tt2 * 16 + row) * XWP + k + 8] = pf1;
        }
    };
    auto XB = [&](f32x4 (&dst)[4], const unsigned short* wbase, int ts) {
        #pragma unroll
        for (int j = 0; j < 4; j++) dst[j] = (f32x4){bv[j], bv[j], bv[j], bv[j]};
        const unsigned short* ab = wbase + (ts * 16 + lm) * XWP + kb * 8;
        #pragma unroll
        for (int kt = 0; kt < XKT; kt++) {
            const short8 a = *(const short8*)(ab + kt * 32);
            dst[0] = __builtin_amdgcn_mfma_f32_16x16x32_bf16(a, bf[0][kt], dst[0], 0, 0, 0);
            dst[1] = __builtin_amdgcn_mfma_f32_16x16x32_bf16(a, bf[1][kt], dst[1], 0, 0, 0);
            dst[2] = __builtin_amdgcn_mfma_f32_16x16x32_bf16(a, bf[2][kt], dst[2], 0, 0, 0);
            dst[3] = __builtin_amdgcn_mfma_f32_16x16x32_bf16(a, bf[3][kt], dst[3], 0, 0, 0);
        }
    };
    auto HM = [&](f32x4 (&a)[4], int par) {
        const unsigned short* hbase = hb + par * HBSZ + lm * HBP + kb * 8;
        #pragma unroll
        for (int kt = 0; kt < HKT; kt++) {
            const short8 av = *(const short8*)(hbase + kt * 32);
            a[0] = __builtin_amdgcn_mfma_f32_16x16x32_bf16(av, bf[0][XKT + kt], a[0], 0, 0, 0);
            a[1] = __builtin_amdgcn_mfma_f32_16x16x32_bf16(av, bf[1][XKT + kt], a[1], 0, 0, 0);
            a[2] = __builtin_amdgcn_mfma_f32_16x16x32_bf16(av, bf[2][XKT + kt], a[2], 0, 0, 0);
            a[3] = __builtin_amdgcn_mfma_f32_16x16x32_bf16(av, bf[3][XKT + kt], a[3], 0, 0, 0);
        }
    };
    auto EPI = [&](f32x4 (&a)[4], int tl) {
        float hv[4];
        #pragma unroll
        for (int r = 0; r < 4; r++) {
            const float ef = __builtin_amdgcn_exp2f(NLOG2E * a[1][r]);
            const float fv = __builtin_amdgcn_rcpf(1.f + ef);
            const float ea = __builtin_amdgcn_exp2f(NLOG2E * a[0][r]);
            const float g2 = fmaxf(a[2][r], -30.f);
            const float eg = __builtin_amdgcn_exp2f(N2LOG2E * g2);
            const float ig = (1.f - eg) * __builtin_amdgcn_rcpf((1.f + ea) * (1.f + eg));
            c[r] = fv * c[r] + ig;
            const float eo = __builtin_amdgcn_exp2f(NLOG2E * a[3][r]);
            const float cc = fmaxf(c[r], -30.f);
            const float ec = __builtin_amdgcn_exp2f(N2LOG2E * cc);
            hv[r] = (1.f - ec) * __builtin_amdgcn_rcpf((1.f + eo) * (1.f + ec));
            hlast[r] = hv[r];
        }
        unsigned p01, p23;   // packed bf16 pairs, RNE
        asm("v_cvt_pk_bf16_f32 %0, %1, %2" : "=v"(p01) : "v"(hv[0]), "v"(hv[1]));
        asm("v_cvt_pk_bf16_f32 %0, %1, %2" : "=v"(p23) : "v"(hv[2]), "v"(hv[3]));
        const unsigned short h0 = (unsigned short)(p01 & 0xffffu);
        const unsigned short h1 = (unsigned short)(p01 >> 16);
        const unsigned short h2 = (unsigned short)(p23 & 0xffffu);
        const unsigned short h3 = (unsigned short)(p23 >> 16);
        unsigned short* hw = hb + ((tl + 1) & 1) * HBSZ + (kb * 4) * HBP + u;
        hw[0] = h0; hw[HBP] = h1; hw[2 * HBP] = h2; hw[3 * HBP] = h3;
        if (IS_L1) {
            unsigned short* op = out1 + (((size_t)(grp * 16 + kb * 4)) * TT + tl) * HH + u;
            op[0] = h0;
            op[(size_t)TT * HH] = h1;
            op[(size_t)2 * TT * HH] = h2;
            op[(size_t)3 * TT * HH] = h3;
        }
    };

    // ---- preamble: window-0 prefetch+commit, then prefetch window 1 ----
    if (!IS_L1) wait_flag(&f_in[0], t);   // covers steps 0..15 (chunk 0)
    PREFETCH(0);
    COMMIT(0);
    PREFETCH(WT);                      // invariant: regs hold W(tw+WT) at step 3
    bar_lds();

    for (int tw = 0; tw < TT; tw += WT) {
        const unsigned short* wbase = xw + ((tw >> 2) & 1) * XBUF;
        const int wst = tw + WT;           // next window start (commit target)
        const int pnext = tw + 2 * WT;     // prefetch target (refills regs)
        f32x4 xc0[4], xc1[4], xn0[4], xn1[4];

        // ---- step 0 ----
        XB(xc0, wbase, 0);
        XB(xc1, wbase, 1);              // hides under epi0
        HM(xc0, 0);
        EPI(xc0, tw + 0);
        bar_lds();
        // ---- step 1 ----
        XB(xn0, wbase, 2);              // hides under epi1
        HM(xc1, 1);
        EPI(xc1, tw + 1);
        bar_lds();
        // ---- step 2 ----
        XB(xn1, wbase, 3);              // hides under epi2
        HM(xn0, 0);
        EPI(xn0, tw + 2);
        bar_lds();
        // ---- step 3: + window commit & prefetch (merged boundary) ----
        HM(xn1, 1);
        if (wst < TT) COMMIT((wst >> 2) & 1);   // regs = W(wst); other buffer dead
        EPI(xn1, tw + 3);
        if (pnext < TT) {
            if (!IS_L1 && (pnext & (CH - 1)) == 0) wait_flag(&f_in[pnext >> 4], t);
            PREFETCH(pnext);            // consumed at next window's step-3 commit
        }
        if (IS_L1 && ((tw + 3) & (CH - 1)) == (CH - 1)) {
            set_flag(&f_out[(tw + 3) >> 4], t); // fence + barrier + flag
        } else {
            bar_lds();                          // boundary barrier (covers commit)
        }
    }

    if (!IS_L1) {
        #pragma unroll
        for (int r = 0; r < 4; r++)
            h2s[((size_t)(grp * 16 + kb * 4 + r)) * HH + u] = hlast[r];
    }
}

// bid 0-15: layer-1 (2 groups per block). bid 16-31: layer-2.
// bid and bid+16 share bid%8 -> same XCD for out1 L2-cache locality.
// waves_per_eu(4,4): exactly one 16-wave block per CU -> 128-VGPR budget
// (R8's allocator targeted 8 waves/EU -> 64 VGPR -> 567MB spill traffic).
__global__ __launch_bounds__(1024)
__attribute__((amdgpu_waves_per_eu(4, 4)))
void lstm_pipe(
    const float* __restrict__ x,
    const float* __restrict__ w1_ih, const float* __restrict__ w1_hh,
    const float* __restrict__ b1_ih, const float* __restrict__ b1_hh,
    const float* __restrict__ w2_ih, const float* __restrict__ w2_hh,
    const float* __restrict__ b2_ih, const float* __restrict__ b2_hh,
    unsigned short* __restrict__ out1, float* __restrict__ h2s,
    int* __restrict__ flags)
{
    __shared__ __align__(16) unsigned short xw[2][2 * WT * 16 * (HH + 8)]; // 69632 B
    __shared__ __align__(16) unsigned short hb[2][2 * HBSZ];               // 17408 B
    const int bid = blockIdx.x;
    const int half = threadIdx.x >> 9;       // wave-uniform
    const int t = threadIdx.x & 511;
    if (bid < 16) {
        const int grp = bid * 2 + half;
        layer_scan<FF, true >(x, w1_ih, w1_hh, b1_ih, b1_hh, out1, nullptr,
                              nullptr, &flags[grp * 32], grp, xw[half], hb[half], t);
    } else {
        const int grp = (bid - 16) * 2 + half;
        layer_scan<HH, false>(out1, w2_ih, w2_hh, b2_ih, b2_hh, nullptr, h2s,
                              &flags[grp * 32], nullptr, grp, xw[half], hb[half], t);
    }
}

__global__ void final_kernel(const float* __restrict__ h2s,
                             const float* __restrict__ w_fc,
                             const float* __restrict__ b_fc,
                             float* __restrict__ out)
{
    const int idx = blockIdx.x * blockDim.x + threadIdx.x;
    if (idx >= BB * NCLS) return;
    const int b = idx / NCLS, cls = idx % NCLS;
    const float* hp = h2s + (size_t)b * HH;
    const float* wp = w_fc + (size_t)cls * HH;
    float acc = b_fc[cls];
    #pragma unroll 8
    for (int k = 0; k < HH; k++) acc += hp[k] * wp[k];
    const float e = __builtin_amdgcn_exp2f(NLOG2E * acc);
    out[idx] = __builtin_amdgcn_rcpf(1.0f + e);
}

extern "C" void kernel_launch(void* const* d_in, const int* in_sizes, int n_in,
                              void* d_out, int out_size, void* d_ws, size_t ws_size,
                              hipStream_t stream)
{
    const float* x     = (const float*)d_in[0];
    const float* w1_ih = (const float*)d_in[1];
    const float* w1_hh = (const float*)d_in[2];
    const float* b1_ih = (const float*)d_in[3];
    const float* b1_hh = (const float*)d_in[4];
    const float* w2_ih = (const float*)d_in[5];
    const float* w2_hh = (const float*)d_in[6];
    const float* b2_ih = (const float*)d_in[7];
    const float* b2_hh = (const float*)d_in[8];
    const float* w_fc  = (const float*)d_in[9];
    const float* b_fc  = (const float*)d_in[10];
    float* out = (float*)d_out;

    // workspace: [h2s fp32 256KB | flags 4KB | out1 bf16 67MB]
    char* ws = (char*)d_ws;
    float* h2s = (float*)ws;                 ws += (size_t)BB * HH * sizeof(float);
    int* flags = (int*)ws;                   ws += 32 * 32 * sizeof(int);
    unsigned short* out1 = (unsigned short*)ws;

    hipMemsetAsync(flags, 0, 32 * 32 * sizeof(int), stream);
    lstm_pipe<<<32, 1024, 0, stream>>>(x, w1_ih, w1_hh, b1_ih, b1_hh,
                                       w2_ih, w2_hh, b2_ih, b2_hh,
                                       out1, h2s, flags);
    final_kernel<<<(BB * NCLS + 255) / 256, 256, 0, stream>>>(h2s, w_fc, b_fc, out);
}

// Round 10
// 910.757 us; speedup vs baseline: 6.4274x; 6.4062x over previous
//
#include <hip/hip_runtime.h>

#define BB 512
#define TT 512
#define FF 64
#define HH 128
#define NCLS 10
#define WT 4            // LDS staging window (steps)
#define CH 16           // producer->consumer chunk (steps)
#define HBP 136         // padded h row (shorts): 272 B, 16B-divisible
#define HBSZ (16 * HBP)
#define NBLK 64         // blocks per layer (8 batch rows each)

typedef __attribute__((ext_vector_type(8))) short short8;
typedef __attribute__((ext_vector_type(4))) float f32x4;

#define NLOG2E  (-1.4426950408889634f)
#define N2LOG2E (-2.8853900817779268f)

__device__ __forceinline__ unsigned short f2bf(float f) {
    union { float f; unsigned u; } v; v.f = f;
    unsigned r = v.u + 0x7FFFu + ((v.u >> 16) & 1u);   // RNE
    return (unsigned short)(r >> 16);
}

// LDS-only barrier: drain lgkmcnt + raw s_barrier (no vmcnt drain).
__device__ __forceinline__ void bar_lds() {
    asm volatile("s_waitcnt lgkmcnt(0)" ::: "memory");
    __builtin_amdgcn_s_barrier();
    asm volatile("" ::: "memory");
}

// ---- flag protocol --------------------------------------------------------
__device__ __forceinline__ void wait_flag(int* f) {
    if (threadIdx.x == 0) {
        while (__hip_atomic_load(f, __ATOMIC_ACQUIRE, __HIP_MEMORY_SCOPE_AGENT) == 0)
            __builtin_amdgcn_s_sleep(2);
    }
    __syncthreads();
    (void)__hip_atomic_load(f, __ATOMIC_ACQUIRE, __HIP_MEMORY_SCOPE_AGENT);
}
__device__ __forceinline__ void set_flag(int* f) {
    __threadfence();
    __syncthreads();   // doubles as the boundary barrier on chunk-end steps
    if (threadIdx.x == 0)
        __hip_atomic_fetch_add(f, 1, __ATOMIC_RELEASE, __HIP_MEMORY_SCOPE_AGENT);
}

// ---------------------------------------------------------------------------
// R10 = R7 (8-row blocks, 128 blocks, full-wave epilogue redistribution) with
// the ONLY unverifiable piece -- permlane32_swap -- replaced by __shfl +
// select. Lanes>=32 take acc regs {2,3} of lane l-32 (rows kb*4+{2,3});
// lanes<32 keep regs {0,1} (rows kb*4+{0,1}). Each lane finishes 2 unit-rows
// -> 16 trans/lane-step (was 32). MFMA tile is M=16 with rows 8..15 zero-
// padded (xw/hb pad rows zeroed once, never written). Bias rides as the
// C-operand of the first x-MFMA. All other structure verbatim R6/R7.
// This is a controlled A/B isolating permlane as R7's failure cause.
// ---------------------------------------------------------------------------
template<int XW, bool IS_L1>
__device__ void layer_scan(
    const void* __restrict__ xin_,
    const float* __restrict__ w_ih, const float* __restrict__ w_hh,
    const float* __restrict__ b_ih, const float* __restrict__ b_hh,
    unsigned short* __restrict__ out1,   // L1: h stream out (bf16)
    float* __restrict__ h2s,             // L2: final h out (fp32)
    int* __restrict__ f_in,              // L2: per-chunk input flags
    int* __restrict__ f_out,             // L1: per-chunk done flags
    int bg, unsigned short* xw, unsigned short* hb)
{
    const int tid = threadIdx.x;
    const int w = tid >> 6, l = tid & 63, lm = l & 15, kb = l >> 4;
    const int u = w * 16 + lm;           // owned hidden unit
    // epilogue rows after redistribution: lanes<32 keep regs {0,1}
    // (rows kb*4+{0,1}); lanes>=32 take regs {2,3} of lane l-32.
    const int row0 = ((l >> 4) & 1) * 4 + (l >> 5) * 2;   // in {0,2,4,6}
    constexpr int KT  = (XW + HH) / 32;  // 6 (L1) / 8 (L2)
    constexpr int XKT = XW / 32;         // 2 / 4
    constexpr int HKT = HH / 32;         // 4
    constexpr int XWP = XW + 8;          // padded LDS row (shorts)
    constexpr int XBUF = WT * 16 * XWP;  // one window buffer (shorts)

    // --- stationary B fragments + broadcast bias: gate g = j*128 + u ---
    short8 bf[4][KT];
    f32x4 bvv[4];
    #pragma unroll
    for (int j = 0; j < 4; j++) {
        const int g = j * 128 + u;
        const float bvf = b_ih[g] + b_hh[g];
        bvv[j] = (f32x4){bvf, bvf, bvf, bvf};
        #pragma unroll
        for (int kt = 0; kt < KT; kt++) {
            const int k0 = kt * 32 + kb * 8;
            const float* s = (k0 < XW) ? (w_ih + (size_t)g * XW + k0)
                                       : (w_hh + (size_t)g * HH + (k0 - XW));
            short8 t;
            #pragma unroll
            for (int q = 0; q < 8; q++) t[q] = (short)f2bf(s[q]);
            bf[j][kt] = t;
        }
    }

    // zero ALL staging LDS once: pad rows 8-15 (never written again) must be 0
    for (int i = tid; i < 2 * XBUF; i += 512) xw[i] = 0;
    for (int i = tid; i < 2 * HBSZ; i += 512) hb[i] = 0;

    float c[2] = {0.f, 0.f}, hlast[2] = {0.f, 0.f};

    float4 pfa;          // L1: 4 fp32
    uint4  pf0;          // L2: 8 bf16

    // ---- helper lambdas (all inlined) ----
    auto PREFETCH = [&](int t0) {
        if (IS_L1) {
            const float* x = (const float*)xin_;
            const int flat = tid * 4;                      // 4 steps x 8 rows x 64
            const int tt2 = flat >> 9, row = (flat >> 6) & 7, k = flat & 63;
            pfa = *(const float4*)(x + (((size_t)(bg * 8 + row)) * TT + t0 + tt2) * FF + k);
        } else {
            const unsigned short* o1 = (const unsigned short*)xin_;
            const int flat = tid * 8;                      // 4 steps x 8 rows x 128
            const int tt2 = flat >> 10, row = (flat >> 7) & 7, k = flat & 127;
            pf0 = *(const uint4*)(o1 + (((size_t)(bg * 8 + row)) * TT + t0 + tt2) * HH + k);
        }
    };
    auto COMMIT = [&](int bufidx) {
        unsigned short* buf = xw + bufidx * XBUF;
        if (IS_L1) {
            const int flat = tid * 4;
            const int tt2 = flat >> 9, row = (flat >> 6) & 7, k = flat & 63;
            uint2 pv;
            pv.x = (unsigned)f2bf(pfa.x) | ((unsigned)f2bf(pfa.y) << 16);
            pv.y = (unsigned)f2bf(pfa.z) | ((unsigned)f2bf(pfa.w) << 16);
            *(uint2*)&buf[(tt2 * 16 + row) * XWP + k] = pv;
        } else {
            const int flat = tid * 8;
            const int tt2 = flat >> 10, row = (flat >> 7) & 7, k = flat & 127;
            *(uint4*)&buf[(tt2 * 16 + row) * XWP + k] = pf0;
        }
    };
    auto XB = [&](f32x4 (&dst)[4], const unsigned short* wbase, int ts) {
        const unsigned short* ab = wbase + (ts * 16 + lm) * XWP + kb * 8;
        {   // first k-tile: bias rides as the C operand (identical numerics)
            const short8 a = *(const short8*)ab;
            dst[0] = __builtin_amdgcn_mfma_f32_16x16x32_bf16(a, bf[0][0], bvv[0], 0, 0, 0);
            dst[1] = __builtin_amdgcn_mfma_f32_16x16x32_bf16(a, bf[1][0], bvv[1], 0, 0, 0);
            dst[2] = __builtin_amdgcn_mfma_f32_16x16x32_bf16(a, bf[2][0], bvv[2], 0, 0, 0);
            dst[3] = __builtin_amdgcn_mfma_f32_16x16x32_bf16(a, bf[3][0], bvv[3], 0, 0, 0);
        }
        #pragma unroll
        for (int kt = 1; kt < XKT; kt++) {
            const short8 a = *(const short8*)(ab + kt * 32);
            dst[0] = __builtin_amdgcn_mfma_f32_16x16x32_bf16(a, bf[0][kt], dst[0], 0, 0, 0);
            dst[1] = __builtin_amdgcn_mfma_f32_16x16x32_bf16(a, bf[1][kt], dst[1], 0, 0, 0);
            dst[2] = __builtin_amdgcn_mfma_f32_16x16x32_bf16(a, bf[2][kt], dst[2], 0, 0, 0);
            dst[3] = __builtin_amdgcn_mfma_f32_16x16x32_bf16(a, bf[3][kt], dst[3], 0, 0, 0);
        }
    };
    auto HM = [&](f32x4 (&a)[4], int par) {
        const unsigned short* hbase = hb + par * HBSZ + lm * HBP + kb * 8;
        #pragma unroll
        for (int kt = 0; kt < HKT; kt++) {
            const short8 av = *(const short8*)(hbase + kt * 32);
            a[0] = __builtin_amdgcn_mfma_f32_16x16x32_bf16(av, bf[0][XKT + kt], a[0], 0, 0, 0);
            a[1] = __builtin_amdgcn_mfma_f32_16x16x32_bf16(av, bf[1][XKT + kt], a[1], 0, 0, 0);
            a[2] = __builtin_amdgcn_mfma_f32_16x16x32_bf16(av, bf[2][XKT + kt], a[2], 0, 0, 0);
            a[3] = __builtin_amdgcn_mfma_f32_16x16x32_bf16(av, bf[3][XKT + kt], a[3], 0, 0, 0);
        }
    };
    auto ROW = [&](const float (&g)[4], float& cr, float& hv) {
        const float ef = __builtin_amdgcn_exp2f(NLOG2E * g[1]);
        const float fv = __builtin_amdgcn_rcpf(1.f + ef);
        const float ea = __builtin_amdgcn_exp2f(NLOG2E * g[0]);
        const float g2 = fmaxf(g[2], -30.f);
        const float eg = __builtin_amdgcn_exp2f(N2LOG2E * g2);
        const float ig = (1.f - eg) * __builtin_amdgcn_rcpf((1.f + ea) * (1.f + eg));
        cr = fv * cr + ig;
        const float eo = __builtin_amdgcn_exp2f(NLOG2E * g[3]);
        const float cc = fmaxf(cr, -30.f);
        const float ec = __builtin_amdgcn_exp2f(N2LOG2E * cc);
        hv = (1.f - ec) * __builtin_amdgcn_rcpf((1.f + eo) * (1.f + ec));
    };
    auto EPI = [&](f32x4 (&a)[4], int tl) {
        // redistribute via __shfl (ds_bpermute): lanes>=32 fetch regs {2,3}
        // of lane l-32; lanes<32 keep regs {0,1}.
        const bool hi = (l >= 32);
        float e0[4], e1[4];
        #pragma unroll
        for (int j = 0; j < 4; j++) {
            const float s2 = __shfl(a[j][2], l & 31, 64);
            const float s3 = __shfl(a[j][3], l & 31, 64);
            e0[j] = hi ? s2 : a[j][0];
            e1[j] = hi ? s3 : a[j][1];
        }
        float h0v, h1v;
        ROW(e0, c[0], h0v);
        ROW(e1, c[1], h1v);
        hlast[0] = h0v; hlast[1] = h1v;
        unsigned p01;
        asm("v_cvt_pk_bf16_f32 %0, %1, %2" : "=v"(p01) : "v"(h0v), "v"(h1v));
        const unsigned short h16_0 = (unsigned short)(p01 & 0xffffu);
        const unsigned short h16_1 = (unsigned short)(p01 >> 16);
        unsigned short* hw = hb + ((tl + 1) & 1) * HBSZ + row0 * HBP + u;
        hw[0] = h16_0; hw[HBP] = h16_1;
        if (IS_L1) {
            unsigned short* op = out1 + (((size_t)(bg * 8 + row0)) * TT + tl) * HH + u;
            op[0] = h16_0;
            op[(size_t)TT * HH] = h16_1;
        }
    };

    // ---- preamble: zero visible -> commit window 0 -> prefetch window 1 ----
    if (!IS_L1) wait_flag(&f_in[0]);   // covers steps 0..15 (chunk 0)
    PREFETCH(0);
    bar_lds();                         // zero-fill visible before first reads
    COMMIT(0);
    PREFETCH(WT);                      // invariant: regs hold W(tw+WT) at step 3
    bar_lds();

    for (int tw = 0; tw < TT; tw += WT) {
        const unsigned short* wbase = xw + ((tw >> 2) & 1) * XBUF;
        const int wst = tw + WT;           // next window start (commit target)
        const int pnext = tw + 2 * WT;     // prefetch target (refills regs)
        f32x4 xc0[4], xc1[4], xn0[4], xn1[4];

        // ---- step 0 ----
        XB(xc0, wbase, 0);
        XB(xc1, wbase, 1);              // hides under epi0
        HM(xc0, 0);
        EPI(xc0, tw + 0);
        bar_lds();
        // ---- step 1 ----
        XB(xn0, wbase, 2);              // hides under epi1
        HM(xc1, 1);
        EPI(xc1, tw + 1);
        bar_lds();
        // ---- step 2 ----
        XB(xn1, wbase, 3);              // hides under epi2
        HM(xn0, 0);
        EPI(xn0, tw + 2);
        bar_lds();
        // ---- step 3: + window commit & prefetch (merged boundary) ----
        HM(xn1, 1);
        if (wst < TT) COMMIT((wst >> 2) & 1);   // regs = W(wst); other buffer dead
        EPI(xn1, tw + 3);
        if (pnext < TT) {
            if (!IS_L1 && (pnext & (CH - 1)) == 0) wait_flag(&f_in[pnext >> 4]);
            PREFETCH(pnext);            // consumed at next window's step-3 commit
        }
        if (IS_L1 && ((tw + 3) & (CH - 1)) == (CH - 1)) {
            set_flag(&f_out[(tw + 3) >> 4]);    // fence + barrier + flag
        } else {
            bar_lds();                          // boundary barrier (covers commit)
        }
    }

    if (!IS_L1) {
        h2s[((size_t)(bg * 8 + row0)) * HH + u]     = hlast[0];
        h2s[((size_t)(bg * 8 + row0 + 1)) * HH + u] = hlast[1];
    }
}

// bid 0-63: layer-1 scan (producer, 8 rows each). bid 64-127: layer-2 scan.
// bid and bid+64 share bid%8 -> same XCD for out1 L2-cache locality.
__global__ __launch_bounds__(512, 1) void lstm_pipe(
    const float* __restrict__ x,
    const float* __restrict__ w1_ih, const float* __restrict__ w1_hh,
    const float* __restrict__ b1_ih, const float* __restrict__ b1_hh,
    const float* __restrict__ w2_ih, const float* __restrict__ w2_hh,
    const float* __restrict__ b2_ih, const float* __restrict__ b2_hh,
    unsigned short* __restrict__ out1, float* __restrict__ h2s,
    int* __restrict__ flags)
{
    __shared__ __align__(16) unsigned short xw[2 * WT * 16 * (HH + 8)]; // 34816 B (L2 max)
    __shared__ __align__(16) unsigned short hb[2 * HBSZ];               //  8704 B
    const int bid = blockIdx.x;
    if (bid < NBLK)
        layer_scan<FF, true >(x, w1_ih, w1_hh, b1_ih, b1_hh, out1, nullptr,
                              nullptr, &flags[bid * 32], bid, xw, hb);
    else
        layer_scan<HH, false>(out1, w2_ih, w2_hh, b2_ih, b2_hh, nullptr, h2s,
                              &flags[(bid - NBLK) * 32], nullptr, bid - NBLK, xw, hb);
}

__global__ void final_kernel(const float* __restrict__ h2s,
                             const float* __restrict__ w_fc,
                             const float* __restrict__ b_fc,
                             float* __restrict__ out)
{
    const int idx = blockIdx.x * blockDim.x + threadIdx.x;
    if (idx >= BB * NCLS) return;
    const int b = idx / NCLS, cls = idx % NCLS;
    const float* hp = h2s + (size_t)b * HH;
    const float* wp = w_fc + (size_t)cls * HH;
    float acc = b_fc[cls];
    #pragma unroll 8
    for (int k = 0; k < HH; k++) acc += hp[k] * wp[k];
    const float e = __builtin_amdgcn_exp2f(NLOG2E * acc);
    out[idx] = __builtin_amdgcn_rcpf(1.0f + e);
}

extern "C" void kernel_launch(void* const* d_in, const int* in_sizes, int n_in,
                              void* d_out, int out_size, void* d_ws, size_t ws_size,
                              hipStream_t stream)
{
    const float* x     = (const float*)d_in[0];
    const float* w1_ih = (const float*)d_in[1];
    const float* w1_hh = (const float*)d_in[2];
    const float* b1_ih = (const float*)d_in[3];
    const float* b1_hh = (const float*)d_in[4];
    const float* w2_ih = (const float*)d_in[5];
    const float* w2_hh = (const float*)d_in[6];
    const float* b2_ih = (const float*)d_in[7];
    const float* b2_hh = (const float*)d_in[8];
    const float* w_fc  = (const float*)d_in[9];
    const float* b_fc  = (const float*)d_in[10];
    float* out = (float*)d_out;

    // workspace: [h2s fp32 256KB | flags 8KB | out1 bf16 67MB]
    char* ws = (char*)d_ws;
    float* h2s = (float*)ws;                 ws += (size_t)BB * HH * sizeof(float);
    int* flags = (int*)ws;                   ws += NBLK * 32 * sizeof(int);
    unsigned short* out1 = (unsigned short*)ws;

    hipMemsetAsync(flags, 0, NBLK * 32 * sizeof(int), stream);
    lstm_pipe<<<2 * NBLK, 512, 0, stream>>>(x, w1_ih, w1_hh, b1_ih, b1_hh,
                                            w2_ih, w2_hh, b2_ih, b2_hh,
                                            out1, h2s, flags);
    final_kernel<<<(BB * NCLS + 255) / 256, 256, 0, stream>>>(h2s, w_fc, b_fc, out);
}

// Round 13
// 765.597 us; speedup vs baseline: 7.6460x; 1.1896x over previous
//
#include <hip/hip_runtime.h>

#define BB 512
#define TT 512
#define FF 64
#define HH 128
#define NCLS 10
#define WT 4            // LDS staging window (steps)
#define CH 16           // producer->consumer chunk (steps)
#define HBP 136         // padded h row (shorts): 272 B, 16B-divisible
#define HBSZ (16 * HBP)

typedef __attribute__((ext_vector_type(8))) short short8;
typedef __attribute__((ext_vector_type(4))) float f32x4;

#define NLOG2E  (-1.4426950408889634f)
#define N2LOG2E (-2.8853900817779268f)

__device__ __forceinline__ unsigned short f2bf(float f) {
    union { float f; unsigned u; } v; v.f = f;
    unsigned r = v.u + 0x7FFFu + ((v.u >> 16) & 1u);   // RNE
    return (unsigned short)(r >> 16);
}

// LDS-only barrier: drain lgkmcnt + raw s_barrier (no vmcnt drain).
__device__ __forceinline__ void bar_lds() {
    asm volatile("s_waitcnt lgkmcnt(0)" ::: "memory");
    __builtin_amdgcn_s_barrier();
    asm volatile("" ::: "memory");
}

// ---- flag protocol --------------------------------------------------------
__device__ __forceinline__ void wait_flag(int* f) {
    if (threadIdx.x == 0) {
        while (__hip_atomic_load(f, __ATOMIC_ACQUIRE, __HIP_MEMORY_SCOPE_AGENT) == 0)
            __builtin_amdgcn_s_sleep(2);
    }
    __syncthreads();
    (void)__hip_atomic_load(f, __ATOMIC_ACQUIRE, __HIP_MEMORY_SCOPE_AGENT);
}
__device__ __forceinline__ void set_flag(int* f) {
    __threadfence();
    __syncthreads();   // doubles as the boundary barrier on chunk-end steps
    if (threadIdx.x == 0)
        __hip_atomic_fetch_add(f, 1, __ATOMIC_RELEASE, __HIP_MEMORY_SCOPE_AGENT);
}

// ---------------------------------------------------------------------------
// R13 = R11 resubmitted verbatim (R11 and R12 both died to infra failures,
// not kernel verdicts; barrier/flag structure is identical to passing R6).
// R11 = R6 + (a) bias-as-C-operand of the first x-MFMA (R10-proven
// bit-exact), (b) manual EPI/XB interleave: each step is HM(cur) then a blend
// [ROW0, XBkt0, ROW1, XBkt1, ROW2, (XBkt2), ROW3, (XBkt3), pack+store].
// Rationale (R10+R3 counters): waves are barrier-locked into an MFMA phase
// (XB+HM) followed by a VALU phase (EPI) -> pipes used sequentially
// (930 + 1430 cyc/SIMD-step). Interleaving next-step XB MFMAs between the
// trans chains of EPI lets matrix + trans pipes overlap. Pure reordering of
// independent ops; per-accumulator FP order identical to R6.
// ---------------------------------------------------------------------------
template<int XW, bool IS_L1>
__device__ void layer_scan(
    const void* __restrict__ xin_,
    const float* __restrict__ w_ih, const float* __restrict__ w_hh,
    const float* __restrict__ b_ih, const float* __restrict__ b_hh,
    unsigned short* __restrict__ out1,   // L1: h stream out (bf16)
    float* __restrict__ h2s,             // L2: final h out (fp32)
    int* __restrict__ f_in,              // L2: per-chunk input flags
    int* __restrict__ f_out,             // L1: per-chunk done flags
    int bg, unsigned short* xw, unsigned short* hb)
{
    const int tid = threadIdx.x;
    const int w = tid >> 6, l = tid & 63, lm = l & 15, kb = l >> 4;
    const int u = w * 16 + lm;           // owned hidden unit
    constexpr int KT  = (XW + HH) / 32;  // 6 (L1) / 8 (L2)
    constexpr int XKT = XW / 32;         // 2 / 4
    constexpr int HKT = HH / 32;         // 4
    constexpr int XWP = XW + 8;          // padded LDS row (shorts)
    constexpr int XBUF = WT * 16 * XWP;  // one window buffer (shorts)

    // --- stationary B fragments + broadcast bias: gate g = j*128 + u ---
    short8 bf[4][KT];
    f32x4 bvv[4];
    #pragma unroll
    for (int j = 0; j < 4; j++) {
        const int g = j * 128 + u;
        const float bvf = b_ih[g] + b_hh[g];
        bvv[j] = (f32x4){bvf, bvf, bvf, bvf};
        #pragma unroll
        for (int kt = 0; kt < KT; kt++) {
            const int k0 = kt * 32 + kb * 8;
            const float* s = (k0 < XW) ? (w_ih + (size_t)g * XW + k0)
                                       : (w_hh + (size_t)g * HH + (k0 - XW));
            short8 t;
            #pragma unroll
            for (int q = 0; q < 8; q++) t[q] = (short)f2bf(s[q]);
            bf[j][kt] = t;
        }
    }

    for (int i = tid; i < 2 * HBSZ; i += 512) hb[i] = 0;

    float c[4] = {0.f, 0.f, 0.f, 0.f}, hlast[4] = {0.f, 0.f, 0.f, 0.f};

    float4 pfa, pfb;     // L1: 8 fp32
    uint4  pf0, pf1;     // L2: 16 bf16

    // ---- helper lambdas (all inlined) ----
    auto PREFETCH = [&](int t0) {
        if (IS_L1) {
            const float* x = (const float*)xin_;
            const int flat = tid * 8;
            const int tt2 = flat >> 10, row = (flat >> 6) & 15, k = flat & 63;
            const float* s = x + (((size_t)(bg * 16 + row)) * TT + t0 + tt2) * FF + k;
            pfa = *(const float4*)s; pfb = *(const float4*)(s + 4);
        } else {
            const unsigned short* o1 = (const unsigned short*)xin_;
            const int flat = tid * 16;
            const int tt2 = flat >> 11, row = (flat >> 7) & 15, k = flat & 127;
            const unsigned short* s = o1 + (((size_t)(bg * 16 + row)) * TT + t0 + tt2) * HH + k;
            pf0 = *(const uint4*)s; pf1 = *(const uint4*)(s + 8);
        }
    };
    auto COMMIT = [&](int bufidx) {
        unsigned short* buf = xw + bufidx * XBUF;
        if (IS_L1) {
            const int flat = tid * 8;
            const int tt2 = flat >> 10, row = (flat >> 6) & 15, k = flat & 63;
            uint4 pv;
            pv.x = (unsigned)f2bf(pfa.x) | ((unsigned)f2bf(pfa.y) << 16);
            pv.y = (unsigned)f2bf(pfa.z) | ((unsigned)f2bf(pfa.w) << 16);
            pv.z = (unsigned)f2bf(pfb.x) | ((unsigned)f2bf(pfb.y) << 16);
            pv.w = (unsigned)f2bf(pfb.z) | ((unsigned)f2bf(pfb.w) << 16);
            *(uint4*)&buf[(tt2 * 16 + row) * XWP + k] = pv;
        } else {
            const int flat = tid * 16;
            const int tt2 = flat >> 11, row = (flat >> 7) & 15, k = flat & 127;
            *(uint4*)&buf[(tt2 * 16 + row) * XWP + k]     = pf0;
            *(uint4*)&buf[(tt2 * 16 + row) * XWP + k + 8] = pf1;
        }
    };
    // one x k-tile group (4 MFMAs); kt==0 carries the bias as the C operand
    auto XBK = [&](f32x4 (&dst)[4], const unsigned short* wbase, int ts, int kt) {
        const unsigned short* ab = wbase + (ts * 16 + lm) * XWP + kb * 8;
        const short8 a = *(const short8*)(ab + kt * 32);
        if (kt == 0) {
            dst[0] = __builtin_amdgcn_mfma_f32_16x16x32_bf16(a, bf[0][0], bvv[0], 0, 0, 0);
            dst[1] = __builtin_amdgcn_mfma_f32_16x16x32_bf16(a, bf[1][0], bvv[1], 0, 0, 0);
            dst[2] = __builtin_amdgcn_mfma_f32_16x16x32_bf16(a, bf[2][0], bvv[2], 0, 0, 0);
            dst[3] = __builtin_amdgcn_mfma_f32_16x16x32_bf16(a, bf[3][0], bvv[3], 0, 0, 0);
        } else {
            dst[0] = __builtin_amdgcn_mfma_f32_16x16x32_bf16(a, bf[0][kt], dst[0], 0, 0, 0);
            dst[1] = __builtin_amdgcn_mfma_f32_16x16x32_bf16(a, bf[1][kt], dst[1], 0, 0, 0);
            dst[2] = __builtin_amdgcn_mfma_f32_16x16x32_bf16(a, bf[2][kt], dst[2], 0, 0, 0);
            dst[3] = __builtin_amdgcn_mfma_f32_16x16x32_bf16(a, bf[3][kt], dst[3], 0, 0, 0);
        }
    };
    auto HM = [&](f32x4 (&a)[4], int par) {
        const unsigned short* hbase = hb + par * HBSZ + lm * HBP + kb * 8;
        #pragma unroll
        for (int kt = 0; kt < HKT; kt++) {
            const short8 av = *(const short8*)(hbase + kt * 32);
            a[0] = __builtin_amdgcn_mfma_f32_16x16x32_bf16(av, bf[0][XKT + kt], a[0], 0, 0, 0);
            a[1] = __builtin_amdgcn_mfma_f32_16x16x32_bf16(av, bf[1][XKT + kt], a[1], 0, 0, 0);
            a[2] = __builtin_amdgcn_mfma_f32_16x16x32_bf16(av, bf[2][XKT + kt], a[2], 0, 0, 0);
            a[3] = __builtin_amdgcn_mfma_f32_16x16x32_bf16(av, bf[3][XKT + kt], a[3], 0, 0, 0);
        }
    };
    // one row's activation chain (identical op sequence to R6)
    auto ROW1 = [&](const f32x4 (&a)[4], int r, float& cr, float& hv) {
        const float ef = __builtin_amdgcn_exp2f(NLOG2E * a[1][r]);
        const float fv = __builtin_amdgcn_rcpf(1.f + ef);
        const float ea = __builtin_amdgcn_exp2f(NLOG2E * a[0][r]);
        const float g2 = fmaxf(a[2][r], -30.f);
        const float eg = __builtin_amdgcn_exp2f(N2LOG2E * g2);
        const float ig = (1.f - eg) * __builtin_amdgcn_rcpf((1.f + ea) * (1.f + eg));
        cr = fv * cr + ig;
        const float eo = __builtin_amdgcn_exp2f(NLOG2E * a[3][r]);
        const float cc = fmaxf(cr, -30.f);
        const float ec = __builtin_amdgcn_exp2f(N2LOG2E * cc);
        hv = (1.f - ec) * __builtin_amdgcn_rcpf((1.f + eo) * (1.f + ec));
    };
    auto PACKSTORE = [&](const float (&hv)[4], int tl) {
        unsigned p01, p23;   // packed bf16 pairs, RNE
        asm("v_cvt_pk_bf16_f32 %0, %1, %2" : "=v"(p01) : "v"(hv[0]), "v"(hv[1]));
        asm("v_cvt_pk_bf16_f32 %0, %1, %2" : "=v"(p23) : "v"(hv[2]), "v"(hv[3]));
        const unsigned short h0 = (unsigned short)(p01 & 0xffffu);
        const unsigned short h1 = (unsigned short)(p01 >> 16);
        const unsigned short h2 = (unsigned short)(p23 & 0xffffu);
        const unsigned short h3 = (unsigned short)(p23 >> 16);
        unsigned short* hw = hb + ((tl + 1) & 1) * HBSZ + (kb * 4) * HBP + u;
        hw[0] = h0; hw[HBP] = h1; hw[2 * HBP] = h2; hw[3 * HBP] = h3;
        if (IS_L1) {
            unsigned short* op = out1 + (((size_t)(bg * 16 + kb * 4)) * TT + tl) * HH + u;
            op[0] = h0;
            op[(size_t)TT * HH] = h1;
            op[(size_t)2 * TT * HH] = h2;
            op[(size_t)3 * TT * HH] = h3;
        }
    };
    // blended step: HM(cur) then EPI rows interleaved with next-step XB k-tiles
    auto STEP = [&](f32x4 (&cur)[4], int tl, int par,
                    f32x4 (&nxt)[4], const unsigned short* wbase, int nts, bool doXB) {
        HM(cur, par);
        float hv[4];
        ROW1(cur, 0, c[0], hv[0]);
        if (doXB)            XBK(nxt, wbase, nts, 0);
        ROW1(cur, 1, c[1], hv[1]);
        if (doXB && 1 < XKT) XBK(nxt, wbase, nts, 1);
        ROW1(cur, 2, c[2], hv[2]);
        if (doXB && 2 < XKT) XBK(nxt, wbase, nts, 2);
        ROW1(cur, 3, c[3], hv[3]);
        if (doXB && 3 < XKT) XBK(nxt, wbase, nts, 3);
        hlast[0] = hv[0]; hlast[1] = hv[1]; hlast[2] = hv[2]; hlast[3] = hv[3];
        PACKSTORE(hv, tl);
    };

    // ---- preamble: window-0 prefetch+commit, then prefetch window 1 ----
    if (!IS_L1) wait_flag(&f_in[0]);   // covers steps 0..15 (chunk 0)
    PREFETCH(0);
    COMMIT(0);
    PREFETCH(WT);                      // invariant: regs hold W(tw+WT) at step 3
    bar_lds();

    for (int tw = 0; tw < TT; tw += WT) {
        const unsigned short* wbase = xw + ((tw >> 2) & 1) * XBUF;
        const int wst = tw + WT;           // next window start (commit target)
        const int pnext = tw + 2 * WT;     // prefetch target (refills regs)
        f32x4 xc0[4], xc1[4], xn0[4], xn1[4];

        // ---- step 0: xc0's own x-burst, then blended steps ----
        XBK(xc0, wbase, 0, 0);
        if (1 < XKT) XBK(xc0, wbase, 0, 1);
        if (2 < XKT) XBK(xc0, wbase, 0, 2);
        if (3 < XKT) XBK(xc0, wbase, 0, 3);
        STEP(xc0, tw + 0, 0, xc1, wbase, 1, true);
        bar_lds();
        // ---- step 1 ----
        STEP(xc1, tw + 1, 1, xn0, wbase, 2, true);
        bar_lds();
        // ---- step 2 ----
        STEP(xn0, tw + 2, 0, xn1, wbase, 3, true);
        bar_lds();
        // ---- step 3: + window commit & prefetch (merged boundary) ----
        HM(xn1, 1);
        if (wst < TT) COMMIT((wst >> 2) & 1);   // regs = W(wst); other buffer dead
        {
            float hv[4];
            ROW1(xn1, 0, c[0], hv[0]);
            ROW1(xn1, 1, c[1], hv[1]);
            ROW1(xn1, 2, c[2], hv[2]);
            ROW1(xn1, 3, c[3], hv[3]);
            hlast[0] = hv[0]; hlast[1] = hv[1]; hlast[2] = hv[2]; hlast[3] = hv[3];
            PACKSTORE(hv, tw + 3);
        }
        if (pnext < TT) {
            if (!IS_L1 && (pnext & (CH - 1)) == 0) wait_flag(&f_in[pnext >> 4]);
            PREFETCH(pnext);            // consumed at next window's step-3 commit
        }
        if (IS_L1 && ((tw + 3) & (CH - 1)) == (CH - 1)) {
            set_flag(&f_out[(tw + 3) >> 4]);    // fence + barrier + flag
        } else {
            bar_lds();                          // boundary barrier (covers commit)
        }
    }

    if (!IS_L1) {
        #pragma unroll
        for (int r = 0; r < 4; r++)
            h2s[((size_t)(bg * 16 + kb * 4 + r)) * HH + u] = hlast[r];
    }
}

// bid 0-31: layer-1 scan (producer). bid 32-63: layer-2 scan (consumer).
// bid and bid+32 share bid%8 -> same XCD for out1 L2-cache locality.
__global__ __launch_bounds__(512, 1) void lstm_pipe(
    const float* __restrict__ x,
    const float* __restrict__ w1_ih, const float* __restrict__ w1_hh,
    const float* __restrict__ b1_ih, const float* __restrict__ b1_hh,
    const float* __restrict__ w2_ih, const float* __restrict__ w2_hh,
    const float* __restrict__ b2_ih, const float* __restrict__ b2_hh,
    unsigned short* __restrict__ out1, float* __restrict__ h2s,
    int* __restrict__ flags)
{
    __shared__ __align__(16) unsigned short xw[2 * WT * 16 * (HH + 8)]; // 34816 B (L2 max)
    __shared__ __align__(16) unsigned short hb[2 * HBSZ];               //  8704 B
    const int bid = blockIdx.x;
    if (bid < 32)
        layer_scan<FF, true >(x, w1_ih, w1_hh, b1_ih, b1_hh, out1, nullptr,
                              nullptr, &flags[bid * 32], bid, xw, hb);
    else
        layer_scan<HH, false>(out1, w2_ih, w2_hh, b2_ih, b2_hh, nullptr, h2s,
                              &flags[(bid - 32) * 32], nullptr, bid - 32, xw, hb);
}

__global__ void final_kernel(const float* __restrict__ h2s,
                             const float* __restrict__ w_fc,
                             const float* __restrict__ b_fc,
                             float* __restrict__ out)
{
    const int idx = blockIdx.x * blockDim.x + threadIdx.x;
    if (idx >= BB * NCLS) return;
    const int b = idx / NCLS, cls = idx % NCLS;
    const float* hp = h2s + (size_t)b * HH;
    const float* wp = w_fc + (size_t)cls * HH;
    float acc = b_fc[cls];
    #pragma unroll 8
    for (int k = 0; k < HH; k++) acc += hp[k] * wp[k];
    const float e = __builtin_amdgcn_exp2f(NLOG2E * acc);
    out[idx] = __builtin_amdgcn_rcpf(1.0f + e);
}

extern "C" void kernel_launch(void* const* d_in, const int* in_sizes, int n_in,
                              void* d_out, int out_size, void* d_ws, size_t ws_size,
                              hipStream_t stream)
{
    const float* x     = (const float*)d_in[0];
    const float* w1_ih = (const float*)d_in[1];
    const float* w1_hh = (const float*)d_in[2];
    const float* b1_ih = (const float*)d_in[3];
    const float* b1_hh = (const float*)d_in[4];
    const float* w2_ih = (const float*)d_in[5];
    const float* w2_hh = (const float*)d_in[6];
    const float* b2_ih = (const float*)d_in[7];
    const float* b2_hh = (const float*)d_in[8];
    const float* w_fc  = (const float*)d_in[9];
    const float* b_fc  = (const float*)d_in[10];
    float* out = (float*)d_out;

    // workspace: [h2s fp32 256KB | flags 4KB | out1 bf16 67MB]
    char* ws = (char*)d_ws;
    float* h2s = (float*)ws;                 ws += (size_t)BB * HH * sizeof(float);
    int* flags = (int*)ws;                   ws += 32 * 32 * sizeof(int);
    unsigned short* out1 = (unsigned short*)ws;

    hipMemsetAsync(flags, 0, 32 * 32 * sizeof(int), stream);
    lstm_pipe<<<64, 512, 0, stream>>>(x, w1_ih, w1_hh, b1_ih, b1_hh,
                                      w2_ih, w2_hh, b2_ih, b2_hh,
                                      out1, h2s, flags);
    final_kernel<<<(BB * NCLS + 255) / 256, 256, 0, stream>>>(h2s, w_fc, b_fc, out);
}